// Round 7
// baseline (512.524 us; speedup 1.0000x reference)
//
#include <hip/hip_runtime.h>

// NodeNetwork fused kernel (f32 VALU, f16 h1): 64 nodes/block, 256 threads (4 waves).
// LDS cut to 35.8KB -> 4 blocks/CU (16 waves) by splitting layer-A K into two
// 64-wide halves (x1 region holds feat then hid) and storing h1 as f16.
// Mailbox streamed in sched_barrier-pinned 8-load batches (R4-proven pattern):
// depths 0-1 in P1, 2-9 under P2a, 10-15 under P2b.
constexpr int NB = 64;
constexpr int THREADS = 256;
constexpr int XAS  = 68;    // x1 half-tile row stride (f32): 64 cols + 4 pad
constexpr int X2S  = 68;    // x2/h2 row stride (f32)
constexpr int H1SU = 50;    // h1 row stride in uints (96 f16 cols + 4 pad = 50 u32)

typedef __fp16 half2_t __attribute__((ext_vector_type(2)));

__device__ __forceinline__ float fast_tanh(float x) {
    // tanh(x) = 1 - 2/(exp(2x)+1); v_exp+v_rcp, abs err ~1e-6, saturates to +-1.
    float e = __expf(2.0f * x);
    return 1.0f - 2.0f * __builtin_amdgcn_rcpf(e + 1.0f);
}

__device__ __forceinline__ void fma24(const float4 x, const float* __restrict__ w0,
                                      float* __restrict__ acc) {
    #pragma unroll
    for (int j = 0; j < 24; ++j) acc[j] = fmaf(x.x, w0[j],       acc[j]);
    #pragma unroll
    for (int j = 0; j < 24; ++j) acc[j] = fmaf(x.y, w0[96 + j],  acc[j]);
    #pragma unroll
    for (int j = 0; j < 24; ++j) acc[j] = fmaf(x.z, w0[192 + j], acc[j]);
    #pragma unroll
    for (int j = 0; j < 24; ++j) acc[j] = fmaf(x.w, w0[288 + j], acc[j]);
}

__device__ __forceinline__ void fma16(float x0, float x1, float x2, float x3,
                                      const float* __restrict__ w0,
                                      float* __restrict__ acc) {
    #pragma unroll
    for (int j = 0; j < 16; ++j) acc[j] = fmaf(x0, w0[j],       acc[j]);
    #pragma unroll
    for (int j = 0; j < 16; ++j) acc[j] = fmaf(x1, w0[64 + j],  acc[j]);
    #pragma unroll
    for (int j = 0; j < 16; ++j) acc[j] = fmaf(x2, w0[128 + j], acc[j]);
    #pragma unroll
    for (int j = 0; j < 16; ++j) acc[j] = fmaf(x3, w0[192 + j], acc[j]);
}

__global__ __launch_bounds__(THREADS, 4) void node_net_kernel(
    const float* __restrict__ feat, const float* __restrict__ hid,
    const float* __restrict__ mail,
    const float* __restrict__ w1a, const float* __restrict__ b1a,
    const float* __restrict__ w1b, const float* __restrict__ b1b,
    const float* __restrict__ w2a, const float* __restrict__ b2a,
    const float* __restrict__ w2b, const float* __restrict__ b2b,
    float* __restrict__ out)
{
    __shared__ float ldsA[NB * XAS];   // x1a (feat) -> x1b (hid) -> h1 (f16 overlay)
    __shared__ float ldsB[NB * X2S];   // x2, later h2
    __shared__ float ldsS[NB * 4];     // per-sub partial sumsq

    const int t  = threadIdx.x;
    const int n0 = blockIdx.x * NB;
    const int c4 = t & 15;             // float4 column 0..15
    const int nb = t >> 4;             // node base 0..15; owns nodes nb+16i (mailbox/staging)

    // mailbox chain bases: [N][16][64] -> node stride 256 f4, depth stride 16 f4
    const float4* mb0 = reinterpret_cast<const float4*>(mail) + (size_t)(n0 + nb) * 256 + c4;

    // ---------- P1: stage feat (x1a) + mailbox depths 0-1 ----------
    float4 m0[4], m1[4];
    {
        float4 f[4];
        #pragma unroll
        for (int i = 0; i < 4; ++i)
            f[i] = reinterpret_cast<const float4*>(feat)[(size_t)(n0 + nb + 16*i) * 16 + c4];
        #pragma unroll
        for (int i = 0; i < 4; ++i) {
            const float4* ch = mb0 + (size_t)i * 4096;
            m0[i] = ch[0];
            m1[i] = ch[16];
        }
        #pragma unroll
        for (int i = 0; i < 4; ++i)
            *reinterpret_cast<float4*>(&ldsA[(nb + 16*i) * XAS + c4 * 4]) = f[i];
    }
    __syncthreads();                       // B1: x1a visible (drains all loads)

    const int node = t & 63;
    const int sub  = __builtin_amdgcn_readfirstlane(t >> 6);  // wave id 0..3, uniform

    float4 macc[4];
    #pragma unroll
    for (int i = 0; i < 4; ++i) macc[i] = m0[i] + m1[i];

    float acc1[24];
    {
        const float* b = b1a + sub * 24;
        #pragma unroll
        for (int j = 0; j < 24; ++j) acc1[j] = b[j];
    }

    // ---------- P2a: layer A, k 0..63 (feat half); stream depths 2-9;
    //            prefetch hid into regs during last batch ----------
    float4 hidreg[4];
    {
        const float4* xr = reinterpret_cast<const float4*>(&ldsA[node * XAS]);
        #pragma unroll 1
        for (int b = 0; b < 4; ++b) {
            if (b == 3) {                  // prefetch hid; consumed after B2
                #pragma unroll
                for (int i = 0; i < 4; ++i)
                    hidreg[i] = reinterpret_cast<const float4*>(hid)[(size_t)(n0 + nb + 16*i) * 16 + c4];
            }
            float4 cur[8];
            #pragma unroll
            for (int i = 0; i < 4; ++i) {
                const float4* ch = mb0 + (size_t)i * 4096;
                cur[i]     = ch[(2 + 2*b) * 16];
                cur[4 + i] = ch[(3 + 2*b) * 16];
            }
            __builtin_amdgcn_sched_barrier(0);   // pin: loads issued above
            #pragma unroll
            for (int kk = 0; kk < 4; ++kk) {
                int k4 = b * 4 + kk;             // 0..15 -> w1a rows 0..63
                fma24(xr[k4], w1a + (k4 * 4) * 96 + sub * 24, acc1);
            }
            __builtin_amdgcn_sched_barrier(0);   // pin: consume after FMAs
            #pragma unroll
            for (int i = 0; i < 4; ++i) macc[i] += cur[i] + cur[4 + i];
        }
    }
    __syncthreads();                       // B2: x1a reads done (drains hid loads too)
    #pragma unroll
    for (int i = 0; i < 4; ++i)
        *reinterpret_cast<float4*>(&ldsA[(nb + 16*i) * XAS + c4 * 4]) = hidreg[i];
    __syncthreads();                       // B3: x1b (hid) visible

    // ---------- P2b: layer A, k 64..127 (hid half); stream depths 10-15 ----------
    {
        const float4* xr = reinterpret_cast<const float4*>(&ldsA[node * XAS]);
        auto batch = [&](int d0, int kfrom, int kto) {
            float4 cur[8];
            #pragma unroll
            for (int i = 0; i < 4; ++i) {
                const float4* ch = mb0 + (size_t)i * 4096;
                cur[i]     = ch[d0 * 16];
                cur[4 + i] = ch[(d0 + 1) * 16];
            }
            __builtin_amdgcn_sched_barrier(0);
            for (int kk = kfrom; kk < kto; ++kk)   // w1a rows 64+4*kk
                fma24(xr[kk], w1a + (64 + kk * 4) * 96 + sub * 24, acc1);
            __builtin_amdgcn_sched_barrier(0);
            #pragma unroll
            for (int i = 0; i < 4; ++i) macc[i] += cur[i] + cur[4 + i];
        };
        batch(10, 0, 6);
        batch(12, 6, 11);
        batch(14, 11, 16);
    }
    // x2 complete -> write to ldsB (region untouched until P4)
    #pragma unroll
    for (int i = 0; i < 4; ++i)
        *reinterpret_cast<float4*>(&ldsB[(nb + 16*i) * X2S + c4 * 4]) = macc[i];
    __syncthreads();                       // B4: x1b reads done; x2 visible

    // ---------- write h1 (relu, f16) into region A ----------
    {
        unsigned* hv = reinterpret_cast<unsigned*>(ldsA) + node * H1SU + sub * 12;
        #pragma unroll
        for (int p = 0; p < 12; ++p) {
            float a0 = fmaxf(acc1[2*p],     0.f);
            float a1 = fmaxf(acc1[2*p + 1], 0.f);
            half2_t hp = __builtin_amdgcn_cvt_pkrtz(a0, a1);
            hv[p] = __builtin_bit_cast(unsigned, hp);
        }
    }
    __syncthreads();                       // B5: h1 visible

    // ---------- P3: r1 = tanh(h1 @ w1b + b1b), j-slice of 16 ----------
    float r1v[16];
    {
        float acc[16];
        const float* b = b1b + sub * 16;
        #pragma unroll
        for (int j = 0; j < 16; ++j) acc[j] = b[j];
        const unsigned* hb = reinterpret_cast<const unsigned*>(ldsA) + node * H1SU;
        #pragma unroll 2
        for (int k4 = 0; k4 < 24; ++k4) {
            unsigned u0 = hb[2*k4], u1 = hb[2*k4 + 1];
            half2_t p0 = __builtin_bit_cast(half2_t, u0);
            half2_t p1 = __builtin_bit_cast(half2_t, u1);
            fma16((float)p0.x, (float)p0.y, (float)p1.x, (float)p1.y,
                  w1b + (k4 * 4) * 64 + sub * 16, acc);
        }
        #pragma unroll
        for (int j = 0; j < 16; ++j) r1v[j] = fast_tanh(acc[j]);
    }

    // ---------- P4: h2 = relu(x2 @ w2a + b2a), j-slice of 16 ----------
    float h2v[16];
    {
        float acc[16];
        const float* b = b2a + sub * 16;
        #pragma unroll
        for (int j = 0; j < 16; ++j) acc[j] = b[j];
        const float4* xr = reinterpret_cast<const float4*>(&ldsB[node * X2S]);
        #pragma unroll 2
        for (int k4 = 0; k4 < 16; ++k4) {
            float4 x = xr[k4];
            fma16(x.x, x.y, x.z, x.w, w2a + (k4 * 4) * 64 + sub * 16, acc);
        }
        #pragma unroll
        for (int j = 0; j < 16; ++j) h2v[j] = fmaxf(acc[j], 0.f);
    }
    __syncthreads();                       // B6: x2 reads done; reuse ldsB for h2
    {
        float4* hrow = reinterpret_cast<float4*>(&ldsB[node * X2S + sub * 16]);
        hrow[0] = make_float4(h2v[0],  h2v[1],  h2v[2],  h2v[3]);
        hrow[1] = make_float4(h2v[4],  h2v[5],  h2v[6],  h2v[7]);
        hrow[2] = make_float4(h2v[8],  h2v[9],  h2v[10], h2v[11]);
        hrow[3] = make_float4(h2v[12], h2v[13], h2v[14], h2v[15]);
    }
    __syncthreads();                       // B7: h2 visible

    // ---------- P5: r2 = tanh(h2 @ w2b + b2b), j-slice of 16 ----------
    float r2v[16];
    {
        float acc[16];
        const float* b = b2b + sub * 16;
        #pragma unroll
        for (int j = 0; j < 16; ++j) acc[j] = b[j];
        const float4* hr = reinterpret_cast<const float4*>(&ldsB[node * X2S]);
        #pragma unroll 2
        for (int k4 = 0; k4 < 16; ++k4) {
            float4 x = hr[k4];
            fma16(x.x, x.y, x.z, x.w, w2b + (k4 * 4) * 64 + sub * 16, acc);
        }
        #pragma unroll
        for (int j = 0; j < 16; ++j) r2v[j] = fast_tanh(acc[j]);
    }

    // ---------- P6: row L2 norm + write ----------
    float s = 0.f;
    #pragma unroll
    for (int j = 0; j < 16; ++j) s = fmaf(r1v[j], r1v[j], s);
    #pragma unroll
    for (int j = 0; j < 16; ++j) s = fmaf(r2v[j], r2v[j], s);
    ldsS[node * 4 + sub] = s;
    __syncthreads();                       // B8
    float4 sv = reinterpret_cast<const float4*>(ldsS)[node];
    float rn = rsqrtf(sv.x + sv.y + sv.z + sv.w);

    float* orow = out + (size_t)(n0 + node) * 128;
    float4* o1 = reinterpret_cast<float4*>(orow + sub * 16);
    float4* o2 = reinterpret_cast<float4*>(orow + 64 + sub * 16);
    #pragma unroll
    for (int j4 = 0; j4 < 4; ++j4) {
        o1[j4] = make_float4(r1v[j4*4+0]*rn, r1v[j4*4+1]*rn, r1v[j4*4+2]*rn, r1v[j4*4+3]*rn);
        o2[j4] = make_float4(r2v[j4*4+0]*rn, r2v[j4*4+1]*rn, r2v[j4*4+2]*rn, r2v[j4*4+3]*rn);
    }
}

extern "C" void kernel_launch(void* const* d_in, const int* in_sizes, int n_in,
                              void* d_out, int out_size, void* d_ws, size_t ws_size,
                              hipStream_t stream) {
    const float* feat = (const float*)d_in[0];
    const float* hid  = (const float*)d_in[1];
    const float* mail = (const float*)d_in[2];
    const float* w1a  = (const float*)d_in[3];
    const float* b1a  = (const float*)d_in[4];
    const float* w1b  = (const float*)d_in[5];
    const float* b1b  = (const float*)d_in[6];
    const float* w2a  = (const float*)d_in[7];
    const float* b2a  = (const float*)d_in[8];
    const float* w2b  = (const float*)d_in[9];
    const float* b2b  = (const float*)d_in[10];
    float* out = (float*)d_out;

    const int N = in_sizes[0] / 64;          // 200000
    const int blocks = N / NB;               // 3125

    node_net_kernel<<<blocks, THREADS, 0, stream>>>(
        feat, hid, mail, w1a, b1a, w1b, b1b, w2a, b2a, w2b, b2b, out);
}

// Round 8
// 239.929 us; speedup vs baseline: 2.1362x; 2.1362x over previous
//
#include <hip/hip_runtime.h>

// NodeNetwork fused kernel: 64 nodes/block, 256 threads (4 waves).
// R4 structure (proven 279us) with x1 and h1 stored as f16 in LDS:
// LDS 52.2KB -> 35.3KB -> 4 blocks/CU (16 waves/CU). No launch_bounds
// min-waves (R7 lesson: it causes catastrophic spills). Mailbox streamed in
// sched_barrier-pinned 8-load batches under layer-A FMAs (R4-proven).
constexpr int NB = 64;
constexpr int THREADS = 256;
constexpr int X1SU = 66;   // x1 row stride in u32 (128 f16 + 4 pad)
constexpr int H1SU = 50;   // h1 row stride in u32 (96 f16 + 4 pad), aliases x1 region
constexpr int X2S  = 68;   // x2/h2 row stride (f32)

typedef __fp16 half2_t __attribute__((ext_vector_type(2)));

__device__ __forceinline__ float fast_tanh(float x) {
    // tanh(x) = 1 - 2/(exp(2x)+1); v_exp+v_rcp, abs err ~1e-6, saturates to +-1.
    float e = __expf(2.0f * x);
    return 1.0f - 2.0f * __builtin_amdgcn_rcpf(e + 1.0f);
}

__device__ __forceinline__ unsigned pk16(float a, float b) {
    half2_t h = __builtin_amdgcn_cvt_pkrtz(a, b);
    return __builtin_bit_cast(unsigned, h);
}

__device__ __forceinline__ void fma24(float x0, float x1, float x2, float x3,
                                      const float* __restrict__ w0,
                                      float* __restrict__ acc) {
    #pragma unroll
    for (int j = 0; j < 24; ++j) acc[j] = fmaf(x0, w0[j],       acc[j]);
    #pragma unroll
    for (int j = 0; j < 24; ++j) acc[j] = fmaf(x1, w0[96 + j],  acc[j]);
    #pragma unroll
    for (int j = 0; j < 24; ++j) acc[j] = fmaf(x2, w0[192 + j], acc[j]);
    #pragma unroll
    for (int j = 0; j < 24; ++j) acc[j] = fmaf(x3, w0[288 + j], acc[j]);
}

__device__ __forceinline__ void fma16(float x0, float x1, float x2, float x3,
                                      const float* __restrict__ w0,
                                      float* __restrict__ acc) {
    #pragma unroll
    for (int j = 0; j < 16; ++j) acc[j] = fmaf(x0, w0[j],       acc[j]);
    #pragma unroll
    for (int j = 0; j < 16; ++j) acc[j] = fmaf(x1, w0[64 + j],  acc[j]);
    #pragma unroll
    for (int j = 0; j < 16; ++j) acc[j] = fmaf(x2, w0[128 + j], acc[j]);
    #pragma unroll
    for (int j = 0; j < 16; ++j) acc[j] = fmaf(x3, w0[192 + j], acc[j]);
}

__global__ __launch_bounds__(THREADS) void node_net_kernel(
    const float* __restrict__ feat, const float* __restrict__ hid,
    const float* __restrict__ mail,
    const float* __restrict__ w1a, const float* __restrict__ b1a,
    const float* __restrict__ w1b, const float* __restrict__ b1b,
    const float* __restrict__ w2a, const float* __restrict__ b2a,
    const float* __restrict__ w2b, const float* __restrict__ b2b,
    float* __restrict__ out)
{
    __shared__ unsigned ldsA[NB * X1SU];   // x1 f16, later h1 f16
    __shared__ float    ldsB[NB * X2S];    // x2, later h2 (f32)
    __shared__ float    ldsS[NB * 4];      // per-sub partial sumsq

    const int t  = threadIdx.x;
    const int n0 = blockIdx.x * NB;
    const int c4 = t & 15;             // float4 column 0..15
    const int nb = t >> 4;             // node base 0..15; owns nodes nb+16c (mailbox/staging)

    // mailbox chain bases: [N][16][64] -> node stride 256 f4, depth stride 16 f4
    const float4* mb0 = reinterpret_cast<const float4*>(mail) + (size_t)(n0 + nb) * 256 + c4;

    // ---------- Phase 1: stage x1 = [feat|hid] as f16 ----------
    #pragma unroll
    for (int i = 0; i < 4; ++i) {
        int n = nb + 16 * i;
        float4 f = reinterpret_cast<const float4*>(feat)[(size_t)(n0 + n) * 16 + c4];
        float4 g = reinterpret_cast<const float4*>(hid )[(size_t)(n0 + n) * 16 + c4];
        unsigned* dst = &ldsA[n * X1SU];
        *reinterpret_cast<uint2*>(dst + c4 * 2)      = make_uint2(pk16(f.x, f.y), pk16(f.z, f.w));
        *reinterpret_cast<uint2*>(dst + 32 + c4 * 2) = make_uint2(pk16(g.x, g.y), pk16(g.z, g.w));
    }
    __syncthreads();                       // B1: x1 visible

    const int node = t & 63;
    const int sub  = __builtin_amdgcn_readfirstlane(t >> 6);  // wave id 0..3, uniform

    // ---------- Phase 2: h1 = relu(x1 @ w1a + b1a), j-slice of 24,
    //            with mailbox streaming pinned under the FMA stream ----------
    float acc1[24];
    {
        const float* b = b1a + sub * 24;
        #pragma unroll
        for (int j = 0; j < 24; ++j) acc1[j] = b[j];
    }
    {
        const unsigned* xr = &ldsA[node * X1SU];
        #pragma unroll 1
        for (int c = 0; c < 4; ++c) {                      // chain c: node nb+16c
            const float4* chain = mb0 + (size_t)c * 4096;  // 16 nodes * 256 f4
            float4 m;
            #pragma unroll
            for (int half = 0; half < 2; ++half) {         // depths [8*half, 8*half+8)
                float4 cur[8];
                #pragma unroll
                for (int d = 0; d < 8; ++d)
                    cur[d] = chain[(half * 8 + d) * 16];
                __builtin_amdgcn_sched_barrier(0);         // pin: loads issued above
                // 4 k4-iterations (384 FMAs) run while the 8 loads are in flight
                #pragma unroll
                for (int kk = 0; kk < 4; ++kk) {
                    int k4 = (c * 2 + half) * 4 + kk;
                    uint2 xu = *reinterpret_cast<const uint2*>(xr + 2 * k4);
                    half2_t p0 = __builtin_bit_cast(half2_t, xu.x);
                    half2_t p1 = __builtin_bit_cast(half2_t, xu.y);
                    fma24((float)p0.x, (float)p0.y, (float)p1.x, (float)p1.y,
                          w1a + (k4 * 4) * 96 + sub * 24, acc1);
                }
                __builtin_amdgcn_sched_barrier(0);         // pin: consume below FMAs
                float4 s = ((cur[0] + cur[1]) + (cur[2] + cur[3]))
                         + ((cur[4] + cur[5]) + (cur[6] + cur[7]));
                if (half == 0) m = s; else m += s;         // static (half unrolled)
            }
            // x2 row for node nb+16c done; ldsB untouched until after barrier B2
            *reinterpret_cast<float4*>(&ldsB[(nb + 16 * c) * X2S + c4 * 4]) = m;
        }
    }
    __syncthreads();                     // B2: all x1 reads done; reuse ldsA for h1
    {
        unsigned* hv = &ldsA[node * H1SU + sub * 12];
        #pragma unroll
        for (int p = 0; p < 12; ++p)
            hv[p] = pk16(fmaxf(acc1[2*p], 0.f), fmaxf(acc1[2*p + 1], 0.f));
    }
    __syncthreads();                     // B3: h1 visible

    // ---------- Phase 3: r1 = tanh(h1 @ w1b + b1b), j-slice of 16 ----------
    float r1v[16];
    {
        float acc[16];
        const float* b = b1b + sub * 16;
        #pragma unroll
        for (int j = 0; j < 16; ++j) acc[j] = b[j];
        const unsigned* hb = &ldsA[node * H1SU];
        #pragma unroll 2
        for (int k4 = 0; k4 < 24; ++k4) {
            uint2 hu = *reinterpret_cast<const uint2*>(hb + 2 * k4);
            half2_t p0 = __builtin_bit_cast(half2_t, hu.x);
            half2_t p1 = __builtin_bit_cast(half2_t, hu.y);
            fma16((float)p0.x, (float)p0.y, (float)p1.x, (float)p1.y,
                  w1b + (k4 * 4) * 64 + sub * 16, acc);
        }
        #pragma unroll
        for (int j = 0; j < 16; ++j) r1v[j] = fast_tanh(acc[j]);
    }

    // ---------- Phase 4: h2 = relu(x2 @ w2a + b2a), j-slice of 16 ----------
    float h2v[16];
    {
        float acc[16];
        const float* b = b2a + sub * 16;
        #pragma unroll
        for (int j = 0; j < 16; ++j) acc[j] = b[j];
        const float4* xr = reinterpret_cast<const float4*>(&ldsB[node * X2S]);
        #pragma unroll 2
        for (int k4 = 0; k4 < 16; ++k4) {
            float4 x = xr[k4];
            fma16(x.x, x.y, x.z, x.w, w2a + (k4 * 4) * 64 + sub * 16, acc);
        }
        #pragma unroll
        for (int j = 0; j < 16; ++j) h2v[j] = fmaxf(acc[j], 0.f);
    }
    __syncthreads();                     // B4: x2 reads done; reuse ldsB for h2
    {
        float4* hrow = reinterpret_cast<float4*>(&ldsB[node * X2S + sub * 16]);
        hrow[0] = make_float4(h2v[0],  h2v[1],  h2v[2],  h2v[3]);
        hrow[1] = make_float4(h2v[4],  h2v[5],  h2v[6],  h2v[7]);
        hrow[2] = make_float4(h2v[8],  h2v[9],  h2v[10], h2v[11]);
        hrow[3] = make_float4(h2v[12], h2v[13], h2v[14], h2v[15]);
    }
    __syncthreads();                     // B5: h2 visible

    // ---------- Phase 5: r2 = tanh(h2 @ w2b + b2b), j-slice of 16 ----------
    float r2v[16];
    {
        float acc[16];
        const float* b = b2b + sub * 16;
        #pragma unroll
        for (int j = 0; j < 16; ++j) acc[j] = b[j];
        const float4* hr = reinterpret_cast<const float4*>(&ldsB[node * X2S]);
        #pragma unroll 2
        for (int k4 = 0; k4 < 16; ++k4) {
            float4 x = hr[k4];
            fma16(x.x, x.y, x.z, x.w, w2b + (k4 * 4) * 64 + sub * 16, acc);
        }
        #pragma unroll
        for (int j = 0; j < 16; ++j) r2v[j] = fast_tanh(acc[j]);
    }

    // ---------- Phase 6: row L2 norm + write ----------
    float s = 0.f;
    #pragma unroll
    for (int j = 0; j < 16; ++j) s = fmaf(r1v[j], r1v[j], s);
    #pragma unroll
    for (int j = 0; j < 16; ++j) s = fmaf(r2v[j], r2v[j], s);
    ldsS[node * 4 + sub] = s;
    __syncthreads();                     // B6
    float4 sv = reinterpret_cast<const float4*>(ldsS)[node];
    float rn = rsqrtf(sv.x + sv.y + sv.z + sv.w);

    float* orow = out + (size_t)(n0 + node) * 128;
    float4* o1 = reinterpret_cast<float4*>(orow + sub * 16);
    float4* o2 = reinterpret_cast<float4*>(orow + 64 + sub * 16);
    #pragma unroll
    for (int j4 = 0; j4 < 4; ++j4) {
        o1[j4] = make_float4(r1v[j4*4+0]*rn, r1v[j4*4+1]*rn, r1v[j4*4+2]*rn, r1v[j4*4+3]*rn);
        o2[j4] = make_float4(r2v[j4*4+0]*rn, r2v[j4*4+1]*rn, r2v[j4*4+2]*rn, r2v[j4*4+3]*rn);
    }
}

extern "C" void kernel_launch(void* const* d_in, const int* in_sizes, int n_in,
                              void* d_out, int out_size, void* d_ws, size_t ws_size,
                              hipStream_t stream) {
    const float* feat = (const float*)d_in[0];
    const float* hid  = (const float*)d_in[1];
    const float* mail = (const float*)d_in[2];
    const float* w1a  = (const float*)d_in[3];
    const float* b1a  = (const float*)d_in[4];
    const float* w1b  = (const float*)d_in[5];
    const float* b1b  = (const float*)d_in[6];
    const float* w2a  = (const float*)d_in[7];
    const float* b2a  = (const float*)d_in[8];
    const float* w2b  = (const float*)d_in[9];
    const float* b2b  = (const float*)d_in[10];
    float* out = (float*)d_out;

    const int N = in_sizes[0] / 64;          // 200000
    const int blocks = N / NB;               // 3125

    node_net_kernel<<<blocks, THREADS, 0, stream>>>(
        feat, hid, mail, w1a, b1a, w1b, b1b, w2a, b2a, w2b, b2b, out);
}